// Round 7
// baseline (155.833 us; speedup 1.0000x reference)
//
#include <hip/hip_runtime.h>
#include <hip/hip_bf16.h>
#include <math.h>

// Problem constants
#define Bb   32
#define Ss   512
#define Hh   768
#define Dd   64
#define ND   128          // 2*D
#define Mrows (Bb*Ss)     // 16384
#define BIGF  1.0e12f
#define BIG8F 1.25e11f    // BIG/8: same fp32 mantissa as 1e12f, exact shift

typedef __attribute__((ext_vector_type(8))) short short8;   // 8 bf16
typedef __attribute__((ext_vector_type(4))) float floatx4;  // 4 f32 acc

__device__ __forceinline__ short f2bf(float x) {
    unsigned u = __builtin_bit_cast(unsigned, x);
    u = (u + 0x7FFF + ((u >> 16) & 1)) >> 16;   // RNE
    return (short)u;
}

// ---------------------------------------------------------------------------
// Kernel 0: w (768,128) f32 -> wfrag fragment-major bf16:
//   wfrag[((t*24 + c)*64 + lane)*8 + j] ; n = t*16+(lane&15), k = c*32+(lane>>4)*8+j
// + RoPE sin/cos table + zero the reduction partials/counter.
// ---------------------------------------------------------------------------
__global__ __launch_bounds__(256) void prep_kernel(
    const float* __restrict__ w, short* __restrict__ wfrag,
    float2* __restrict__ rt, double* __restrict__ partial,
    unsigned* __restrict__ cnt)
{
    int idx = blockIdx.x * 256 + threadIdx.x;  // 98304 total
    int j    = idx & 7;
    int lane = (idx >> 3) & 63;
    int rest = idx >> 9;                       // t*24 + c
    int c    = rest % 24;
    int t    = rest / 24;
    int n    = t * 16 + (lane & 15);
    int k    = c * 32 + (lane >> 4) * 8 + j;
    wfrag[idx] = f2bf(w[k * ND + n]);
    if (idx < Ss * 32) {
        int spos = idx >> 5;
        int i    = idx & 31;
        float ln_base = -logf(10000.0f) / 32.0f;
        float invf = expf(ln_base * (float)i);
        float sn, cs;
        sincosf((float)spos * invf, &sn, &cs);
        rt[idx] = make_float2(sn, cs);
    }
    if (idx < 512) partial[idx] = 0.0;
    if (idx == 512) *cnt = 0u;
}

// ---------------------------------------------------------------------------
// Kernel 1: MFMA bf16 projection + bias + RoPE -> q/k (bf16), q pre-scaled
// by 1/8 (exact). Block = 16 rows, 4 waves = 4 K-quarters (6 chunks each);
// each wave computes the FULL 16x128 tile so hidden is fetched ONCE (R6 had
// q- and k-waves double-reading it). Partials combined via LDS.
// __launch_bounds__(256,3): VGPR cap ~170 for the full A+B double buffer
// (compile-time indices only — R3: runtime indices => scratch disaster).
// ---------------------------------------------------------------------------
__global__ __launch_bounds__(256, 3) void proj_rope_kernel(
    const float*  __restrict__ hidden,   // (M, H) f32
    const short*  __restrict__ wfrag,    // fragment-major bf16
    const float*  __restrict__ bias,     // (128,) f32
    const float2* __restrict__ rt,       // (512, 32) sin/cos
    short* __restrict__ qbf,             // (M, 64) bf16, pre-scaled 1/8
    short* __restrict__ kbf)             // (M, 64) bf16
{
    const int tid   = threadIdx.x;
    const int kh    = tid >> 6;          // K quarter 0..3 (chunks kh*6..+5)
    const int lane  = tid & 63;
    const int quad  = lane >> 4;
    const int l15   = lane & 15;
    const int mrow0 = blockIdx.x * 16;

    const float* ap  = hidden + (size_t)(mrow0 + l15) * Hh + quad * 8
                              + kh * 6 * 32;
    const short* bp0 = wfrag + lane * 8 + kh * 6 * 512;

    floatx4 acc[8];
    #pragma unroll
    for (int t = 0; t < 8; ++t) acc[t] = (floatx4){0.f, 0.f, 0.f, 0.f};

    float4 A0[2], A1[2];
    short8 Bf[2][8];

#define PLOAD(buf, c) do {                                          \
    A0[buf] = *(const float4*)(ap + (c) * 32);                      \
    A1[buf] = *(const float4*)(ap + (c) * 32 + 4);                  \
    _Pragma("unroll")                                               \
    for (int t = 0; t < 8; ++t)                                     \
        Bf[buf][t] = *(const short8*)(bp0 + t * 24 * 512 + (c) * 512); \
} while (0)

#define PCOMP(buf) do {                                             \
    short8 av;                                                      \
    av[0] = f2bf(A0[buf].x); av[1] = f2bf(A0[buf].y);               \
    av[2] = f2bf(A0[buf].z); av[3] = f2bf(A0[buf].w);               \
    av[4] = f2bf(A1[buf].x); av[5] = f2bf(A1[buf].y);               \
    av[6] = f2bf(A1[buf].z); av[7] = f2bf(A1[buf].w);               \
    _Pragma("unroll")                                               \
    for (int t = 0; t < 8; ++t)                                     \
        acc[t] = __builtin_amdgcn_mfma_f32_16x16x32_bf16(           \
                     av, Bf[buf][t], acc[t], 0, 0, 0);              \
} while (0)

    PLOAD(0, 0);
    #pragma unroll
    for (int cc = 0; cc < 3; ++cc) {
        PLOAD(1, 2 * cc + 1);
        PCOMP(0);
        if (2 * cc + 2 < 6) PLOAD(0, 2 * cc + 2);
        PCOMP(1);
    }
#undef PLOAD
#undef PCOMP

    // ---- combine the 4 K-quarters through LDS
    __shared__ float lacc[3][32][64];    // [kh-1][t*4+reg][lane]  24 KB
    if (kh) {
        #pragma unroll
        for (int t = 0; t < 8; ++t)
            #pragma unroll
            for (int reg = 0; reg < 4; ++reg)
                lacc[kh - 1][t * 4 + reg][lane] = acc[t][reg];
    }
    __syncthreads();
    if (kh) return;

    #pragma unroll
    for (int t = 0; t < 8; ++t)
        #pragma unroll
        for (int reg = 0; reg < 4; ++reg)
            acc[t][reg] += lacc[0][t * 4 + reg][lane]
                         + lacc[1][t * 4 + reg][lane]
                         + lacc[2][t * 4 + reg][lane];

    // ---- Epilogue: bias + RoPE -> bf16; q additionally scaled by 1/8.
    #pragma unroll
    for (int t = 0; t < 8; ++t) {
        const int n  = t * 16 + l15;               // 0..127
        const int d  = n & (Dd - 1);               // within q/k half
        const float bz = bias[n];
        short* dst = (t < 4) ? qbf : kbf;
        const float2* rtp = rt + (d >> 1);
        #pragma unroll
        for (int reg = 0; reg < 4; ++reg) {
            const int grow = mrow0 + quad * 4 + reg;
            const int spos = grow & (Ss - 1);
            float2 sc = rtp[spos * 32];
            float x  = acc[t][reg] + bz;
            float xo = __shfl_xor(x, 1);
            float o  = (d & 1) ? (x * sc.y + xo * sc.x)
                               : (x * sc.y - xo * sc.x);
            if (t < 4) o *= 0.125f;               // fold 1/sqrt(D) into q
            dst[(size_t)grow * Dd + d] = f2bf(o);
        }
    }
}

// ---------------------------------------------------------------------------
// Kernel 2: MFMA QK^T + masks + dual logsumexp + fused final mean.
// Grid: 32 batches x 16 slices of 32 rows; 512 threads (8 waves).
// Direct span loads hoisted before MFMA (R6 proved span reads are not the
// bottleneck; pack pass was pure overhead). Per-block double partial +
// last-block (counter) final reduction — no 4th kernel.
// ---------------------------------------------------------------------------
__global__ __launch_bounds__(512, 4) void span_loss_kernel(
    const short* __restrict__ qbf,      // (M, 64) bf16, pre-scaled 1/8
    const short* __restrict__ kbf,      // (M, 64) bf16
    const float* __restrict__ mask,     // (B, S)
    const int*   __restrict__ span,     // (B, S, S)
    double* __restrict__ partial,       // (512,)
    unsigned* __restrict__ cnt,
    float* __restrict__ out)
{
    const int b    = blockIdx.x >> 4;
    const int m0   = (blockIdx.x & 15) * 32;
    const int tid  = threadIdx.x;
    const int w    = tid >> 6;
    const int lane = tid & 63;
    const int quad = lane >> 4;
    const int l15  = lane & 15;
    const int rh   = w & 1;              // row half (16 rows)
    const int cg   = w >> 1;             // col group (128 cols)
    const int rbase = m0 + rh * 16;
    const int cbase = cg * 128;

    __shared__ float part[2][4][32];     // [neg/pos][colgroup][row]
    __shared__ float bred[2][32];
    __shared__ int   isLast;

    // ---- hoisted span + mask loads (independent of MFMA results)
    int spv[8][4];
    float pdv[8];
    {
        const int* spp = span + ((size_t)(b * Ss + rbase + quad * 4)) * Ss
                              + cbase + l15;
        #pragma unroll
        for (int t = 0; t < 8; ++t) {
            pdv[t] = mask[b * Ss + cbase + t * 16 + l15];
            #pragma unroll
            for (int reg = 0; reg < 4; ++reg)
                spv[t][reg] = spp[(size_t)reg * Ss + t * 16];
        }
    }

    // ---- A frags (Q): rows rbase + l15
    const short* qp = qbf + (size_t)(b * Ss + rbase + l15) * Dd + quad * 8;
    short8 a0 = *(const short8*)(qp);
    short8 a1 = *(const short8*)(qp + 32);

    floatx4 acc[8];
    #pragma unroll
    for (int t = 0; t < 8; ++t) acc[t] = (floatx4){0.f, 0.f, 0.f, 0.f};

    // ---- B frags (K): cols cbase + t*16 + l15; two K-chunks.
    const short* kp = kbf + (size_t)(b * Ss + cbase + l15) * Dd + quad * 8;
    #pragma unroll
    for (int t = 0; t < 8; ++t) {
        short8 bv = *(const short8*)(kp + (size_t)t * 16 * Dd);
        acc[t] = __builtin_amdgcn_mfma_f32_16x16x32_bf16(a0, bv, acc[t], 0, 0, 0);
    }
    #pragma unroll
    for (int t = 0; t < 8; ++t) {
        short8 bv = *(const short8*)(kp + (size_t)t * 16 * Dd + 32);
        acc[t] = __builtin_amdgcn_mfma_f32_16x16x32_bf16(a1, bv, acc[t], 0, 0, 0);
    }

    // ---- Epilogue: dots (already /8 via q) -> yp in place; pack span bits.
    unsigned spb = 0;
    #pragma unroll
    for (int t = 0; t < 8; ++t) {
        const int n = cbase + t * 16 + l15;
        const float pd = pdv[t];
        #pragma unroll
        for (int reg = 0; reg < 4; ++reg) {
            const int m = rbase + quad * 4 + reg;
            const int sv = spv[t][reg];
            float logit = acc[t][reg] * pd - (1.0f - pd) * BIG8F;
            if (n < m) logit -= BIG8F;
            float ft = (float)sv;
            acc[t][reg] = (1.0f - 2.0f * ft) * logit;   // yp
            spb |= (unsigned)(sv != 0) << (t * 4 + reg);
        }
    }

    // ---- Pass 1: max (zero entry folded via init 0).
    float mxn[4] = {0.f, 0.f, 0.f, 0.f};
    float mxp[4] = {0.f, 0.f, 0.f, 0.f};
    #pragma unroll
    for (int t = 0; t < 8; ++t) {
        #pragma unroll
        for (int reg = 0; reg < 4; ++reg) {
            float ft = (float)((spb >> (t * 4 + reg)) & 1u);
            float yp = acc[t][reg];
            mxn[reg] = fmaxf(mxn[reg], yp - ft * BIGF);
            mxp[reg] = fmaxf(mxp[reg], yp - (1.0f - ft) * BIGF);
        }
    }
    #pragma unroll
    for (int off = 1; off < 16; off <<= 1) {
        #pragma unroll
        for (int reg = 0; reg < 4; ++reg) {
            mxn[reg] = fmaxf(mxn[reg], __shfl_xor(mxn[reg], off));
            mxp[reg] = fmaxf(mxp[reg], __shfl_xor(mxp[reg], off));
        }
    }
    if (l15 == 0) {
        #pragma unroll
        for (int reg = 0; reg < 4; ++reg) {
            part[0][cg][rh * 16 + quad * 4 + reg] = mxn[reg];
            part[1][cg][rh * 16 + quad * 4 + reg] = mxp[reg];
        }
    }
    __syncthreads();
    if (tid < 64) {
        int np = tid >> 5, r = tid & 31;
        float mv = fmaxf(fmaxf(part[np][0][r], part[np][1][r]),
                         fmaxf(part[np][2][r], part[np][3][r]));
        bred[np][r] = mv;
    }
    __syncthreads();

    // ---- Pass 2: sum of exp(v - max).
    float bmn[4], bmp[4];
    #pragma unroll
    for (int reg = 0; reg < 4; ++reg) {
        bmn[reg] = bred[0][rh * 16 + quad * 4 + reg];
        bmp[reg] = bred[1][rh * 16 + quad * 4 + reg];
    }
    float smn[4] = {0.f, 0.f, 0.f, 0.f};
    float smp[4] = {0.f, 0.f, 0.f, 0.f};
    #pragma unroll
    for (int t = 0; t < 8; ++t) {
        #pragma unroll
        for (int reg = 0; reg < 4; ++reg) {
            float ft = (float)((spb >> (t * 4 + reg)) & 1u);
            float yp = acc[t][reg];
            smn[reg] += __expf(yp - ft * BIGF - bmn[reg]);
            smp[reg] += __expf(yp - (1.0f - ft) * BIGF - bmp[reg]);
        }
    }
    #pragma unroll
    for (int off = 1; off < 16; off <<= 1) {
        #pragma unroll
        for (int reg = 0; reg < 4; ++reg) {
            smn[reg] += __shfl_xor(smn[reg], off);
            smp[reg] += __shfl_xor(smp[reg], off);
        }
    }
    if (l15 == 0) {
        #pragma unroll
        for (int reg = 0; reg < 4; ++reg) {
            part[0][cg][rh * 16 + quad * 4 + reg] = smn[reg];
            part[1][cg][rh * 16 + quad * 4 + reg] = smp[reg];
        }
    }
    __syncthreads();

    // ---- per-row lse (tid<32), wave-0 double reduce, block partial.
    float lse = 0.0f;
    if (tid < 32) {
        int r = tid;
        float SN = __expf(-bred[0][r])
                 + part[0][0][r] + part[0][1][r] + part[0][2][r] + part[0][3][r];
        float SP = __expf(-bred[1][r])
                 + part[1][0][r] + part[1][1][r] + part[1][2][r] + part[1][3][r];
        lse = (bred[0][r] + logf(SN)) + (bred[1][r] + logf(SP));
    }
    if (tid < 64) {
        double dv = (tid < 32) ? (double)lse : 0.0;
        #pragma unroll
        for (int off = 1; off < 32; off <<= 1) dv += __shfl_xor(dv, off);
        if (tid == 0) {
            partial[blockIdx.x] = dv;
            __threadfence();
            unsigned old = atomicAdd(cnt, 1u);
            isLast = (old == 511u) ? 1 : 0;
        }
    }
    __syncthreads();

    if (isLast && tid < 64) {
        // atomic RMW reads: device-coherent by construction.
        double s = 0.0;
        #pragma unroll
        for (int i = 0; i < 8; ++i)
            s += atomicAdd(&partial[tid + i * 64], 0.0);
        #pragma unroll
        for (int off = 1; off < 64; off <<= 1) s += __shfl_xor(s, off);
        if (tid == 0) out[0] = (float)(s / (double)Mrows);
    }
}

// ---------------------------------------------------------------------------
extern "C" void kernel_launch(void* const* d_in, const int* in_sizes, int n_in,
                              void* d_out, int out_size, void* d_ws, size_t ws_size,
                              hipStream_t stream)
{
    const float* hidden = (const float*)d_in[0];   // (B,S,H)
    const float* mask   = (const float*)d_in[1];   // (B,S)
    const int*   span   = (const int*)  d_in[2];   // (B,S,S)
    const float* w      = (const float*)d_in[3];   // (H, 2D)
    const float* bias   = (const float*)d_in[4];   // (2D,)
    float* out = (float*)d_out;

    // ws layout:
    //  [partial: 512 f64 = 4096 B][cnt: 4 B + pad -> 8192]
    //  [wfrag:  98304 bf16 = 196608 B]
    //  [rt:     16384 float2 = 131072 B]
    //  [qbf:    16384*64 bf16 = 2 MB]
    //  [kbf:    16384*64 bf16 = 2 MB]
    char* p = (char*)d_ws;
    double*   partial = (double*)p;
    unsigned* cnt     = (unsigned*)(p + 4096);
    short*    wfrag   = (short*)(p + 8192);
    float2*   rt      = (float2*)(p + 8192 + 196608);
    short*    qbf     = (short*)(p + 8192 + 196608 + 131072);
    short*    kbf     = qbf + (size_t)Mrows * Dd;

    prep_kernel<<<Hh * ND / 256, 256, 0, stream>>>(w, wfrag, rt, partial, cnt);
    proj_rope_kernel<<<Mrows / 16, 256, 0, stream>>>(hidden, wfrag, bias, rt, qbf, kbf);
    span_loss_kernel<<<Bb * 16, 512, 0, stream>>>(qbf, kbf, mask, span, partial, cnt, out);
}

// Round 8
// 153.044 us; speedup vs baseline: 1.0182x; 1.0182x over previous
//
#include <hip/hip_runtime.h>
#include <hip/hip_bf16.h>
#include <math.h>

// Problem constants
#define Bb   32
#define Ss   512
#define Hh   768
#define Dd   64
#define ND   128          // 2*D
#define Mrows (Bb*Ss)     // 16384
#define BIGF  1.0e12f
#define BIG8F 1.25e11f    // BIG/8: exact power-of-2 scale of 1e12
#define NEGHUGE -1.0e30f  // exp(NEGHUGE - m) == 0.0f exactly, any plausible m

typedef __attribute__((ext_vector_type(8))) short short8;   // 8 bf16
typedef __attribute__((ext_vector_type(4))) float floatx4;  // 4 f32 acc

__device__ __forceinline__ short f2bf(float x) {
    unsigned u = __builtin_bit_cast(unsigned, x);
    u = (u + 0x7FFF + ((u >> 16) & 1)) >> 16;   // RNE
    return (short)u;
}

// ---------------------------------------------------------------------------
// Kernel 0: w (768,128) f32 -> wfrag fragment-major bf16:
//   wfrag[((tt*24 + c)*64 + lane)*8 + j]; n = tt*16+(lane&15), k = c*32+(lane>>4)*8+j
// + RoPE sin/cos table + zero reduction partials/counter.
// ---------------------------------------------------------------------------
__global__ __launch_bounds__(256) void prep_kernel(
    const float* __restrict__ w, short* __restrict__ wfrag,
    float2* __restrict__ rt, double* __restrict__ partial,
    unsigned* __restrict__ cnt)
{
    int idx = blockIdx.x * 256 + threadIdx.x;  // 98304 total
    int j    = idx & 7;
    int lane = (idx >> 3) & 63;
    int rest = idx >> 9;                       // tt*24 + c
    int c    = rest % 24;
    int tt   = rest / 24;
    int n    = tt * 16 + (lane & 15);
    int k    = c * 32 + (lane >> 4) * 8 + j;
    wfrag[idx] = f2bf(w[k * ND + n]);
    if (idx < Ss * 32) {
        int spos = idx >> 5;
        int i    = idx & 31;
        float ln_base = -logf(10000.0f) / 32.0f;
        float invf = expf(ln_base * (float)i);
        float sn, cs;
        sincosf((float)spos * invf, &sn, &cs);
        rt[idx] = make_float2(sn, cs);
    }
    if (idx < 512) partial[idx] = 0.0;
    if (idx == 512) *cnt = 0u;
}

// ---------------------------------------------------------------------------
// Kernel 1: MFMA bf16 projection + bias + RoPE -> q/k (bf16); q pre-scaled
// by 1/8 (exact). R6 structure (empirically best): 512 thr, 8 waves =
// (rowgrp, h, khalf); 12-chunk compile-time double-buffer chains; 2-way
// K-combine via LDS. R7's 4-way-split variant regressed ~12 us (short
// chains + 1-wave epilogue + lower occupancy) — do not repeat.
// __launch_bounds__(512,4): default heuristic would cap VGPRs and demote
// the double buffer to scratch (R4).
// ---------------------------------------------------------------------------
__global__ __launch_bounds__(512, 4) void proj_rope_kernel(
    const float*  __restrict__ hidden,   // (M, H) f32
    const short*  __restrict__ wfrag,    // fragment-major bf16
    const float*  __restrict__ bias,     // (128,) f32
    const float2* __restrict__ rt,       // (512, 32) sin/cos
    short* __restrict__ qbf,             // (M, 64) bf16, pre-scaled 1/8
    short* __restrict__ kbf)             // (M, 64) bf16
{
    const int tid   = threadIdx.x;
    const int w     = tid >> 6;          // wave 0..7
    const int lane  = tid & 63;
    const int quad  = lane >> 4;
    const int l15   = lane & 15;
    const int rg    = w & 1;             // row group (16 rows)
    const int h     = (w >> 1) & 1;      // 0 = q cols, 1 = k cols
    const int kh    = w >> 2;            // K half (chunks kh*12 .. +11)
    const int mrow0 = blockIdx.x * 32 + rg * 16;

    const float* ap  = hidden + (size_t)(mrow0 + l15) * Hh + quad * 8
                              + kh * 12 * 32;
    const short* bp0 = wfrag + (size_t)(h * 4) * 24 * 512 + lane * 8
                             + kh * 12 * 512;

    floatx4 acc[4] = {{0.f,0.f,0.f,0.f},{0.f,0.f,0.f,0.f},
                      {0.f,0.f,0.f,0.f},{0.f,0.f,0.f,0.f}};

    float4 A0[2], A1[2];
    short8 Bf[2][4];

#define PLOAD(buf, c) do {                                        \
    A0[buf] = *(const float4*)(ap + (c) * 32);                    \
    A1[buf] = *(const float4*)(ap + (c) * 32 + 4);                \
    Bf[buf][0] = *(const short8*)(bp0 + 0 * 24 * 512 + (c) * 512);\
    Bf[buf][1] = *(const short8*)(bp0 + 1 * 24 * 512 + (c) * 512);\
    Bf[buf][2] = *(const short8*)(bp0 + 2 * 24 * 512 + (c) * 512);\
    Bf[buf][3] = *(const short8*)(bp0 + 3 * 24 * 512 + (c) * 512);\
} while (0)

#define PCOMP(buf) do {                                         \
    short8 av;                                                  \
    av[0] = f2bf(A0[buf].x); av[1] = f2bf(A0[buf].y);           \
    av[2] = f2bf(A0[buf].z); av[3] = f2bf(A0[buf].w);           \
    av[4] = f2bf(A1[buf].x); av[5] = f2bf(A1[buf].y);           \
    av[6] = f2bf(A1[buf].z); av[7] = f2bf(A1[buf].w);           \
    acc[0] = __builtin_amdgcn_mfma_f32_16x16x32_bf16(av, Bf[buf][0], acc[0], 0, 0, 0); \
    acc[1] = __builtin_amdgcn_mfma_f32_16x16x32_bf16(av, Bf[buf][1], acc[1], 0, 0, 0); \
    acc[2] = __builtin_amdgcn_mfma_f32_16x16x32_bf16(av, Bf[buf][2], acc[2], 0, 0, 0); \
    acc[3] = __builtin_amdgcn_mfma_f32_16x16x32_bf16(av, Bf[buf][3], acc[3], 0, 0, 0); \
} while (0)

    PLOAD(0, 0);
    #pragma unroll
    for (int cc = 0; cc < 6; ++cc) {
        if (2 * cc + 1 < 12) PLOAD(1, 2 * cc + 1);
        PCOMP(0);
        if (2 * cc + 2 < 12) PLOAD(0, 2 * cc + 2);
        PCOMP(1);
    }
#undef PLOAD
#undef PCOMP

    // ---- combine K halves through LDS (slot = rg*2+h = w&3)
    __shared__ float lacc[4][16][64];    // [slot][t*4+reg][lane] 16 KB
    const int slot = w & 3;
    if (kh == 1) {
        #pragma unroll
        for (int t = 0; t < 4; ++t)
            #pragma unroll
            for (int reg = 0; reg < 4; ++reg)
                lacc[slot][t * 4 + reg][lane] = acc[t][reg];
    }
    __syncthreads();
    if (kh == 1) return;

    #pragma unroll
    for (int t = 0; t < 4; ++t)
        #pragma unroll
        for (int reg = 0; reg < 4; ++reg)
            acc[t][reg] += lacc[slot][t * 4 + reg][lane];

    // ---- Epilogue: bias + RoPE (table) -> bf16 store; q scaled by 1/8.
    short* dst = h ? kbf : qbf;
    const float* bptr = bias + h * 64;
    const float qs = h ? 1.0f : 0.125f;

    #pragma unroll
    for (int t = 0; t < 4; ++t) {
        const int d  = t * 16 + l15;               // 0..63 within q/k half
        const float bz = bptr[d];
        const float2* rtp = rt + (d >> 1);
        #pragma unroll
        for (int reg = 0; reg < 4; ++reg) {
            const int grow = mrow0 + quad * 4 + reg;
            const int spos = grow & (Ss - 1);
            float2 sc = rtp[spos * 32];
            float x  = acc[t][reg] + bz;
            float xo = __shfl_xor(x, 1);
            float o  = (d & 1) ? (x * sc.y + xo * sc.x)
                               : (x * sc.y - xo * sc.x);
            dst[(size_t)grow * Dd + d] = f2bf(o * qs);
        }
    }
}

// ---------------------------------------------------------------------------
// Kernel 2: MFMA QK^T + masks + dual logsumexp + fused final mean.
// Grid: 32 batches x 16 slices of 32 rows; 512 threads (8 waves).
// Exactness note: exp(yp - BIG - m) == 0 in fp32 (underflow; the fp32
// reference underflows identically, margin ~1e11 vs the 88 cutoff), so the
// ft-masked side of each pair is replaced by a select against -1e30.
// ---------------------------------------------------------------------------
__global__ __launch_bounds__(512, 4) void span_loss_kernel(
    const short* __restrict__ qbf,      // (M, 64) bf16, pre-scaled 1/8
    const short* __restrict__ kbf,      // (M, 64) bf16
    const float* __restrict__ mask,     // (B, S)
    const int*   __restrict__ span,     // (B, S, S)
    double* __restrict__ partial,       // (512,)
    unsigned* __restrict__ cnt,
    float* __restrict__ out)
{
    const int b    = blockIdx.x >> 4;
    const int m0   = (blockIdx.x & 15) * 32;
    const int tid  = threadIdx.x;
    const int w    = tid >> 6;
    const int lane = tid & 63;
    const int quad = lane >> 4;
    const int l15  = lane & 15;
    const int rh   = w & 1;              // row half (16 rows)
    const int cg   = w >> 1;             // col group (128 cols)
    const int rbase = m0 + rh * 16;
    const int cbase = cg * 128;

    __shared__ float part[2][4][32];     // [neg/pos][colgroup][row]
    __shared__ float bred[2][32];
    __shared__ int   isLast;

    // ---- hoisted span + mask loads (independent of MFMA results)
    int spv[8][4];
    float pdv[8];
    {
        const int* spp = span + ((size_t)(b * Ss + rbase + quad * 4)) * Ss
                              + cbase + l15;
        #pragma unroll
        for (int t = 0; t < 8; ++t) {
            pdv[t] = mask[b * Ss + cbase + t * 16 + l15];
            #pragma unroll
            for (int reg = 0; reg < 4; ++reg)
                spv[t][reg] = spp[(size_t)reg * Ss + t * 16];
        }
    }

    // ---- A frags (Q): rows rbase + l15
    const short* qp = qbf + (size_t)(b * Ss + rbase + l15) * Dd + quad * 8;
    short8 a0 = *(const short8*)(qp);
    short8 a1 = *(const short8*)(qp + 32);

    floatx4 acc[8];
    #pragma unroll
    for (int t = 0; t < 8; ++t) acc[t] = (floatx4){0.f, 0.f, 0.f, 0.f};

    // ---- B frags (K): cols cbase + t*16 + l15; two K-chunks.
    const short* kp = kbf + (size_t)(b * Ss + cbase + l15) * Dd + quad * 8;
    #pragma unroll
    for (int t = 0; t < 8; ++t) {
        short8 bv = *(const short8*)(kp + (size_t)t * 16 * Dd);
        acc[t] = __builtin_amdgcn_mfma_f32_16x16x32_bf16(a0, bv, acc[t], 0, 0, 0);
    }
    #pragma unroll
    for (int t = 0; t < 8; ++t) {
        short8 bv = *(const short8*)(kp + (size_t)t * 16 * Dd + 32);
        acc[t] = __builtin_amdgcn_mfma_f32_16x16x32_bf16(a1, bv, acc[t], 0, 0, 0);
    }

    // ---- Epilogue: dots (already /8 via q) -> yp = (1-2ft)*logit; span bits.
    unsigned spb = 0;
    #pragma unroll
    for (int t = 0; t < 8; ++t) {
        const int n = cbase + t * 16 + l15;
        const float pd = pdv[t];
        #pragma unroll
        for (int reg = 0; reg < 4; ++reg) {
            const int m = rbase + quad * 4 + reg;
            const int sv = spv[t][reg];
            float logit = acc[t][reg] * pd - (1.0f - pd) * BIG8F;
            if (n < m) logit -= BIG8F;
            acc[t][reg] = sv ? -logit : logit;          // yp
            spb |= (unsigned)(sv != 0) << (t * 4 + reg);
        }
    }

    // ---- Pass 1: max (zero entry folded via init 0; masked side -> -1e30).
    float mxn[4] = {0.f, 0.f, 0.f, 0.f};
    float mxp[4] = {0.f, 0.f, 0.f, 0.f};
    #pragma unroll
    for (int t = 0; t < 8; ++t) {
        #pragma unroll
        for (int reg = 0; reg < 4; ++reg) {
            bool f = (spb >> (t * 4 + reg)) & 1u;
            float yp = acc[t][reg];
            mxn[reg] = fmaxf(mxn[reg], f ? NEGHUGE : yp);
            mxp[reg] = fmaxf(mxp[reg], f ? yp : NEGHUGE);
        }
    }
    #pragma unroll
    for (int off = 1; off < 16; off <<= 1) {
        #pragma unroll
        for (int reg = 0; reg < 4; ++reg) {
            mxn[reg] = fmaxf(mxn[reg], __shfl_xor(mxn[reg], off));
            mxp[reg] = fmaxf(mxp[reg], __shfl_xor(mxp[reg], off));
        }
    }
    if (l15 == 0) {
        #pragma unroll
        for (int reg = 0; reg < 4; ++reg) {
            part[0][cg][rh * 16 + quad * 4 + reg] = mxn[reg];
            part[1][cg][rh * 16 + quad * 4 + reg] = mxp[reg];
        }
    }
    __syncthreads();
    if (tid < 64) {
        int np = tid >> 5, r = tid & 31;
        float mv = fmaxf(fmaxf(part[np][0][r], part[np][1][r]),
                         fmaxf(part[np][2][r], part[np][3][r]));
        bred[np][r] = mv;
    }
    __syncthreads();

    // ---- Pass 2: sum of exp(v - max); masked side exps to exactly 0.
    float bmn[4], bmp[4];
    #pragma unroll
    for (int reg = 0; reg < 4; ++reg) {
        bmn[reg] = bred[0][rh * 16 + quad * 4 + reg];
        bmp[reg] = bred[1][rh * 16 + quad * 4 + reg];
    }
    float smn[4] = {0.f, 0.f, 0.f, 0.f};
    float smp[4] = {0.f, 0.f, 0.f, 0.f};
    #pragma unroll
    for (int t = 0; t < 8; ++t) {
        #pragma unroll
        for (int reg = 0; reg < 4; ++reg) {
            bool f = (spb >> (t * 4 + reg)) & 1u;
            float yp = acc[t][reg];
            smn[reg] += __expf((f ? NEGHUGE : yp) - bmn[reg]);
            smp[reg] += __expf((f ? yp : NEGHUGE) - bmp[reg]);
        }
    }
    #pragma unroll
    for (int off = 1; off < 16; off <<= 1) {
        #pragma unroll
        for (int reg = 0; reg < 4; ++reg) {
            smn[reg] += __shfl_xor(smn[reg], off);
            smp[reg] += __shfl_xor(smp[reg], off);
        }
    }
    if (l15 == 0) {
        #pragma unroll
        for (int reg = 0; reg < 4; ++reg) {
            part[0][cg][rh * 16 + quad * 4 + reg] = smn[reg];
            part[1][cg][rh * 16 + quad * 4 + reg] = smp[reg];
        }
    }
    __syncthreads();

    // ---- per-row lse (tid<32), wave-0 double reduce, block partial.
    float lse = 0.0f;
    if (tid < 32) {
        int r = tid;
        float SN = __expf(-bred[0][r])
                 + part[0][0][r] + part[0][1][r] + part[0][2][r] + part[0][3][r];
        float SP = __expf(-bred[1][r])
                 + part[1][0][r] + part[1][1][r] + part[1][2][r] + part[1][3][r];
        lse = (bred[0][r] + logf(SN)) + (bred[1][r] + logf(SP));
    }
    if (tid < 64) {
        double dv = (tid < 32) ? (double)lse : 0.0;
        #pragma unroll
        for (int off = 1; off < 32; off <<= 1) dv += __shfl_xor(dv, off);
        if (tid == 0) {
            partial[blockIdx.x] = dv;
            __threadfence();
            unsigned old = atomicAdd(cnt, 1u);
            isLast = (old == 511u) ? 1 : 0;
        }
    }
    __syncthreads();

    if (isLast && tid < 64) {
        // atomic RMW reads: device-coherent by construction.
        double s = 0.0;
        #pragma unroll
        for (int i = 0; i < 8; ++i)
            s += atomicAdd(&partial[tid + i * 64], 0.0);
        #pragma unroll
        for (int off = 1; off < 64; off <<= 1) s += __shfl_xor(s, off);
        if (tid == 0) out[0] = (float)(s / (double)Mrows);
    }
}

// ---------------------------------------------------------------------------
extern "C" void kernel_launch(void* const* d_in, const int* in_sizes, int n_in,
                              void* d_out, int out_size, void* d_ws, size_t ws_size,
                              hipStream_t stream)
{
    const float* hidden = (const float*)d_in[0];   // (B,S,H)
    const float* mask   = (const float*)d_in[1];   // (B,S)
    const int*   span   = (const int*)  d_in[2];   // (B,S,S)
    const float* w      = (const float*)d_in[3];   // (H, 2D)
    const float* bias   = (const float*)d_in[4];   // (2D,)
    float* out = (float*)d_out;

    // ws layout:
    //  [partial: 512 f64 = 4096 B][cnt: 4 B + pad -> 8192]
    //  [wfrag:  98304 bf16 = 196608 B]
    //  [rt:     16384 float2 = 131072 B]
    //  [qbf:    16384*64 bf16 = 2 MB]
    //  [kbf:    16384*64 bf16 = 2 MB]
    char* p = (char*)d_ws;
    double*   partial = (double*)p;
    unsigned* cnt     = (unsigned*)(p + 4096);
    short*    wfrag   = (short*)(p + 8192);
    float2*   rt      = (float2*)(p + 8192 + 196608);
    short*    qbf     = (short*)(p + 8192 + 196608 + 131072);
    short*    kbf     = qbf + (size_t)Mrows * Dd;

    prep_kernel<<<Hh * ND / 256, 256, 0, stream>>>(w, wfrag, rt, partial, cnt);
    proj_rope_kernel<<<Mrows / 32, 512, 0, stream>>>(hidden, wfrag, bias, rt, qbf, kbf);
    span_loss_kernel<<<Bb * 16, 512, 0, stream>>>(qbf, kbf, mask, span, partial, cnt, out);
}